// Round 5
// baseline (301.486 us; speedup 1.0000x reference)
//
#include <hip/hip_runtime.h>
#include <math.h>

// Problem constants (PointMAE self-attention)
#define DIM   512
#define NH    8
#define HD    64
#define BATCH 8
#define SEQ   1024
// 0.125 * log2(e): folded into Q at the qkv epilogue so attn uses exp2 directly.
#define QSCALE 0.18033688011112042f

typedef unsigned short u16;
typedef unsigned int   u32;
typedef unsigned long long u64;
typedef __bf16 bf16x8 __attribute__((ext_vector_type(8)));
typedef float  f32x4  __attribute__((ext_vector_type(4)));

__device__ inline u16 f2bf(float f) {   // fp32 -> bf16 RNE
  u32 u = __builtin_bit_cast(u32, f);
  return (u16)((u + 0x7fffu + ((u >> 16) & 1u)) >> 16);
}
__device__ inline float bf2f(u16 h) {
  return __builtin_bit_cast(float, (u32)h << 16);
}
__device__ inline u32 pk2(float a, float b) {  // packed RNE bf16 pair
  return (u32)f2bf(a) | ((u32)f2bf(b) << 16);
}

// Async global->LDS, 16 B per lane. LDS side must be base + lane*16.
__device__ inline void a16(const u16* g, u16* l) {
  __builtin_amdgcn_global_load_lds(
      (const __attribute__((address_space(1))) u32*)g,
      (__attribute__((address_space(3))) u32*)l, 16, 0, 0);
}

// Tiled fragment layout for K=512 tensors: elt(m,k) ->
//   (m>>4)*8192 + (k>>3)*128 + (m&15)*8 + (k&7)

// ---------------------------------------------------------------------------
// Kernel 0a: pack mask [B,T,T] int32 -> bitmask uint64, TRANSPOSED layout
// bits[(b*16 + kt)*1024 + qrow] covering keys kt*64..kt*64+63.
// ---------------------------------------------------------------------------
__global__ __launch_bounds__(256) void pack_mask(const int* __restrict__ mask,
                                                 u64* __restrict__ bits) {
  const size_t gid = (size_t)blockIdx.x * 256 + threadIdx.x;
  const int lane = threadIdx.x & 63;
  const size_t w = gid >> 6;                 // word id = (b*1024 + q)*16 + kt
  const int v = mask[w * 64 + lane];
  const u64 b = __ballot(v != 0);
  if (lane == 0) {
    const int bb = (int)(w >> 14), q = (int)((w >> 4) & 1023), kt = (int)(w & 15);
    bits[(((size_t)(bb << 4 | kt)) << 10) | q] = b;
  }
}

// ---------------------------------------------------------------------------
// Kernel 0b: decompose fp32 [R][512] -> bf16 hi/lo in tiled fragment layout.
// ---------------------------------------------------------------------------
__global__ __launch_bounds__(256) void decompose(const float* __restrict__ src,
                                                 u16* __restrict__ hi,
                                                 u16* __restrict__ lo) {
  const int rg = blockIdx.x;
  const int t = threadIdx.x;
  const float* s = src + (size_t)rg * 16 * DIM;
  u16* ph = hi + (size_t)rg * 8192;
  u16* pl = lo + (size_t)rg * 8192;
  #pragma unroll
  for (int c = 0; c < 4; ++c) {
    const int cid = c * 256 + t;        // chunk id = kc*16 + row
    const int row = cid & 15, kc = cid >> 4;
    float f[8];
    *(float4*)&f[0] = *(const float4*)&s[row * DIM + kc * 8];
    *(float4*)&f[4] = *(const float4*)&s[row * DIM + kc * 8 + 4];
    u16 hv[8], lv[8];
    #pragma unroll
    for (int j = 0; j < 8; ++j) {
      hv[j] = f2bf(f[j]);
      lv[j] = f2bf(f[j] - bf2f(hv[j]));
    }
    *(uint4*)&ph[(size_t)cid * 8] = *(const uint4*)hv;
    *(uint4*)&pl[(size_t)cid * 8] = *(const uint4*)lv;
  }
}

// ---------------------------------------------------------------------------
// Kernel 1/3: split-bf16 MFMA GEMM (3-pass: AhBh + AhBl + AlBh), fp32-exact
// to ~2^-18.  A [M][512], B [N][512] tiled hi/lo.  128x128 tile, 4 waves.
// QKV=true: q scaled by QSCALE -> [b,h,t,d]; k -> [b,h,t,d]; v -> [b,h,d,t].
// ---------------------------------------------------------------------------
template <bool QKV>
__global__ __launch_bounds__(256) void mfma_gemm(
    const u16* __restrict__ Agh, const u16* __restrict__ Agl,
    const u16* __restrict__ Bgh, const u16* __restrict__ Bgl,
    const float* __restrict__ bias, void* __restrict__ out0,
    u16* __restrict__ kb, u16* __restrict__ vtb) {
  __shared__ u16 sAh[4096];
  __shared__ u16 sAl[4096];
  __shared__ u16 sBh[4096];
  __shared__ u16 sBl[4096];

  const int tid = threadIdx.x;
  const int lane = tid & 63;
  const int wv = tid >> 6;
  const int lk = lane & 15, lq = lane >> 4;
  const int n0 = blockIdx.x * 128, m0 = blockIdx.y * 128;
  const int wm = (wv & 1) * 4;
  const int wn = (wv >> 1) * 4;

  const u16* gAh = Agh + (size_t)(m0 >> 4) * 8192 + lane * 8;
  const u16* gAl = Agl + (size_t)(m0 >> 4) * 8192 + lane * 8;
  const u16* gBh = Bgh + (size_t)(n0 >> 4) * 8192 + lane * 8;
  const u16* gBl = Bgl + (size_t)(n0 >> 4) * 8192 + lane * 8;

  f32x4 acc[4][4];
  #pragma unroll
  for (int i = 0; i < 4; ++i)
    #pragma unroll
    for (int j = 0; j < 4; ++j) acc[i][j] = (f32x4){0.f, 0.f, 0.f, 0.f};

  #pragma unroll 1
  for (int ki = 0; ki < 16; ++ki) {
    __syncthreads();
    #pragma unroll
    for (int it = 0; it < 2; ++it) {
      const int t = it * 4 + wv;
      const size_t go = (size_t)t * 8192 + ki * 512;
      const int lo_ = t * 512 + lane * 8;
      a16(gAh + go, &sAh[lo_]);
      a16(gAl + go, &sAl[lo_]);
      a16(gBh + go, &sBh[lo_]);
      a16(gBl + go, &sBl[lo_]);
    }
    __syncthreads();

    bf16x8 ah[4], al[4], bh[4], bl[4];
    #pragma unroll
    for (int i = 0; i < 4; ++i) {
      ah[i] = *(const bf16x8*)&sAh[(wm + i) * 512 + lane * 8];
      al[i] = *(const bf16x8*)&sAl[(wm + i) * 512 + lane * 8];
      bh[i] = *(const bf16x8*)&sBh[(wn + i) * 512 + lane * 8];
      bl[i] = *(const bf16x8*)&sBl[(wn + i) * 512 + lane * 8];
    }
    #pragma unroll
    for (int i = 0; i < 4; ++i)
      #pragma unroll
      for (int j = 0; j < 4; ++j) {
        acc[i][j] = __builtin_amdgcn_mfma_f32_16x16x32_bf16(ah[i], bh[j], acc[i][j], 0, 0, 0);
        acc[i][j] = __builtin_amdgcn_mfma_f32_16x16x32_bf16(ah[i], bl[j], acc[i][j], 0, 0, 0);
        acc[i][j] = __builtin_amdgcn_mfma_f32_16x16x32_bf16(al[i], bh[j], acc[i][j], 0, 0, 0);
      }
  }

  // Epilogue. C/D layout: col = lk (n), row = lq*4 + r (m).
  #pragma unroll
  for (int j = 0; j < 4; ++j) {
    const int n = n0 + (wn + j) * 16 + lk;
    const float bv_ = bias[n];
    #pragma unroll
    for (int i = 0; i < 4; ++i) {
      const int mb = m0 + (wm + i) * 16 + lq * 4;
      if (QKV) {
        const int which = n >> 9, h = (n >> 6) & 7, d = n & 63;
        const int b = mb >> 10, tok0 = mb & 1023;
        if (which == 2) {           // V: transposed [b,h,d,t], vector store
          ushort4 o;
          o.x = f2bf(acc[i][j][0] + bv_);
          o.y = f2bf(acc[i][j][1] + bv_);
          o.z = f2bf(acc[i][j][2] + bv_);
          o.w = f2bf(acc[i][j][3] + bv_);
          *(ushort4*)&vtb[(((size_t)((b << 3) + h) << 6 | d) << 10) + tok0] = o;
        } else {                    // Q (scaled) / K: [b,h,t,d]
          u16* dst = which ? kb : (u16*)out0;
          const float sc = which ? 1.0f : QSCALE;
          #pragma unroll
          for (int r = 0; r < 4; ++r)
            dst[(((size_t)((b << 3) + h) << 10 | (tok0 + r)) << 6) + d] =
                f2bf((acc[i][j][r] + bv_) * sc);
        }
      } else {
        #pragma unroll
        for (int r = 0; r < 4; ++r)
          ((float*)out0)[(size_t)(mb + r) * DIM + n] = acc[i][j][r] + bv_;
      }
    }
  }
}

// ---------------------------------------------------------------------------
// Kernel 2: barrier-free flash attention.
// S^T via mfma(A=K, B=Q) so each thread holds 4 k-contiguous P values
// (one ds_write_b64); PV A-frag reads the wave-private P row back.
// K/V/Q fragments load directly from global (V pre-transposed [b,h,d,t]).
// No-max softmax: Q pre-scaled by 0.125*log2e, pv = exp2(s), l summed at end.
// ---------------------------------------------------------------------------
__global__ __launch_bounds__(256) void attn_mfma(
    const u16* __restrict__ qg, const u16* __restrict__ kg,
    const u16* __restrict__ vtg, const u64* __restrict__ bitsT,
    u16* __restrict__ ohi, u16* __restrict__ olo) {
  __shared__ u16 Ps[64 * 72];   // [q][k] stride 72: b128 frag reads 2-way max

  const int tid = threadIdx.x;
  const int lane = tid & 63;
  const int wv = tid >> 6;
  const int lk = lane & 15, lq = lane >> 4;
  const int q0 = blockIdx.x * 64;
  const int bh = blockIdx.y;
  const int bb = bh >> 3;
  const int q = q0 + wv * 16 + lk;        // this thread's softmax row

  // Q B-frags (n=q), hoisted across all k-tiles.
  const u16* qrow = qg + ((size_t)(bh << 10 | q) << 6);
  const bf16x8 bq0 = *(const bf16x8*)(qrow + lq * 8);
  const bf16x8 bq1 = *(const bf16x8*)(qrow + 32 + lq * 8);

  const u16* kbase = kg + ((size_t)bh << 16) + ((size_t)lk << 6) + lq * 8;
  const u16* vbase = vtg + ((size_t)bh << 16) + ((size_t)lk << 10) + lq * 8;
  const u64* bitp = bitsT + ((size_t)bb << 14) + q;
  u16* pw = &Ps[(wv * 16 + lk) * 72];     // wave-private P row (own q)

  f32x4 o_[4];
  float l = 0.f;
  #pragma unroll
  for (int t = 0; t < 4; ++t) o_[t] = (f32x4){0.f, 0.f, 0.f, 0.f};

  #pragma unroll 1
  for (int kt = 0; kt < 16; ++kt) {
    // Direct-from-global MFMA fragments (coalesced dwordx4).
    bf16x8 ak[4][2], bv[4][2];
    #pragma unroll
    for (int t = 0; t < 4; ++t) {
      const u16* kp = kbase + (size_t)((kt * 64 + t * 16) << 6);
      ak[t][0] = *(const bf16x8*)kp;
      ak[t][1] = *(const bf16x8*)(kp + 32);
      const u16* vp = vbase + ((size_t)(t * 16) << 10) + kt * 64;
      bv[t][0] = *(const bf16x8*)vp;
      bv[t][1] = *(const bf16x8*)(vp + 32);
    }
    const u64 wd = bitp[kt << 10];
    const u32 w0 = (u32)wd, w1 = (u32)(wd >> 32);

    // S^T: D[m=k-local][n=q]; thread holds k = t*16 + lq*4 + r for q=own row.
    f32x4 st[4];
    const f32x4 z4 = (f32x4){0.f, 0.f, 0.f, 0.f};
    #pragma unroll
    for (int t = 0; t < 4; ++t) {
      f32x4 a = __builtin_amdgcn_mfma_f32_16x16x32_bf16(ak[t][0], bq0, z4, 0, 0, 0);
      st[t] = __builtin_amdgcn_mfma_f32_16x16x32_bf16(ak[t][1], bq1, a, 0, 0, 0);
    }

    // Masked exp2 (no max subtraction), partial l, packed b64 P writes.
    #pragma unroll
    for (int t = 0; t < 4; ++t) {
      const u32 w = (t < 2) ? w0 : w1;
      const int base = (t & 1) * 16 + lq * 4;
      float p[4];
      #pragma unroll
      for (int r = 0; r < 4; ++r) {
        const float sv = ((w >> (base + r)) & 1u) ? -INFINITY : st[t][r];
        p[r] = __builtin_amdgcn_exp2f(sv);
        l += p[r];
      }
      *(uint2*)(pw + t * 16 + lq * 4) = uint2{pk2(p[0], p[1]), pk2(p[2], p[3])};
    }

    // PV: A = own P row (wave-private, lgkmcnt only, no barrier).
    const bf16x8 pa0 = *(const bf16x8*)(pw + lq * 8);
    const bf16x8 pa1 = *(const bf16x8*)(pw + 32 + lq * 8);
    #pragma unroll
    for (int t = 0; t < 4; ++t) {
      o_[t] = __builtin_amdgcn_mfma_f32_16x16x32_bf16(pa0, bv[t][0], o_[t], 0, 0, 0);
      o_[t] = __builtin_amdgcn_mfma_f32_16x16x32_bf16(pa1, bv[t][1], o_[t], 0, 0, 0);
    }
  }

  // Row-sum l lives split across the 4 lq groups: reduce once.
  l += __shfl_xor(l, 16);
  l += __shfl_xor(l, 32);

  // Epilogue: normalize; emit tiled hi/lo for proj GEMM (k = h*64+d).
  const int h = bh & 7;
  #pragma unroll
  for (int r = 0; r < 4; ++r) {
    const float inv = 1.0f / __shfl(l, lq * 4 + r);
    const int tok = q0 + wv * 16 + lq * 4 + r;
    const int m = (bb << 10) | tok;
    const size_t rgo = (size_t)(m >> 4) * 8192 + (size_t)(m & 15) * 8;
    #pragma unroll
    for (int t = 0; t < 4; ++t) {
      const int d = t * 16 + lk;
      const int k = (h << 6) | d;
      const float v = o_[t][r] * inv;
      const u16 hv = f2bf(v);
      const size_t off = rgo + (size_t)(k >> 3) * 128 + (k & 7);
      ohi[off] = hv;
      olo[off] = f2bf(v - bf2f(hv));
    }
  }
}

// ---------------------------------------------------------------------------
extern "C" void kernel_launch(void* const* d_in, const int* in_sizes, int n_in,
                              void* d_out, int out_size, void* d_ws,
                              size_t ws_size, hipStream_t stream) {
  const float* x      = (const float*)d_in[0];
  const int*   mask   = (const int*)d_in[1];   // jax bool -> int32
  const float* qkv_w  = (const float*)d_in[2];
  const float* qkv_b  = (const float*)d_in[3];
  const float* proj_w = (const float*)d_in[4];
  const float* proj_b = (const float*)d_in[5];
  float* out = (float*)d_out;

  // Workspace: bits | qb kb vtb | xhi xlo | ohi olo | wqh wql | wph wpl
  const size_t SZ = (size_t)BATCH * NH * SEQ * HD;   // 4,194,304 elts
  u64* bits = (u64*)d_ws;                            // 1 MB
  u16* qb  = (u16*)(bits + 131072);
  u16* kb  = qb + SZ;
  u16* vtb = kb + SZ;
  u16* xhi = vtb + SZ;
  u16* xlo = xhi + SZ;
  u16* ohi = xlo + SZ;
  u16* olo = ohi + SZ;
  u16* wqh = olo + SZ;
  u16* wql = wqh + 1536 * 512;
  u16* wph = wql + 1536 * 512;
  u16* wpl = wph + 512 * 512;

  pack_mask<<<(BATCH * SEQ * SEQ) / 256, 256, 0, stream>>>(mask, bits);
  decompose<<<8192 / 16, 256, 0, stream>>>(x, xhi, xlo);
  decompose<<<1536 / 16, 256, 0, stream>>>(qkv_w, wqh, wql);
  decompose<<<512 / 16, 256, 0, stream>>>(proj_w, wph, wpl);

  mfma_gemm<true><<<dim3(12, 64), 256, 0, stream>>>(
      xhi, xlo, wqh, wql, qkv_b, qb, kb, vtb);
  attn_mfma<<<dim3(SEQ / 64, BATCH * NH), 256, 0, stream>>>(
      qb, kb, vtb, bits, ohi, olo);
  mfma_gemm<false><<<dim3(4, 64), 256, 0, stream>>>(
      ohi, olo, wph, wpl, proj_b, out, nullptr, nullptr);
}

// Round 6
// 219.669 us; speedup vs baseline: 1.3725x; 1.3725x over previous
//
#include <hip/hip_runtime.h>
#include <math.h>

// Problem constants (PointMAE self-attention)
#define DIM   512
#define NH    8
#define HD    64
#define BATCH 8
#define SEQ   1024
// 0.125 * log2(e): folded into Q at the qkv epilogue so attn uses exp2 directly.
#define QSCALE 0.18033688011112042f

typedef unsigned short u16;
typedef unsigned int   u32;
typedef unsigned long long u64;
typedef __bf16 bf16x8 __attribute__((ext_vector_type(8)));
typedef float  f32x4  __attribute__((ext_vector_type(4)));

__device__ inline u16 f2bf(float f) {   // fp32 -> bf16 RNE
  u32 u = __builtin_bit_cast(u32, f);
  return (u16)((u + 0x7fffu + ((u >> 16) & 1u)) >> 16);
}
__device__ inline float bf2f(u16 h) {
  return __builtin_bit_cast(float, (u32)h << 16);
}
__device__ inline u32 pk2(float a, float b) {  // packed RNE bf16 pair
  return (u32)f2bf(a) | ((u32)f2bf(b) << 16);
}

// Async global->LDS, 16 B per lane. LDS side must be base + lane*16.
__device__ inline void a16(const u16* g, u16* l) {
  __builtin_amdgcn_global_load_lds(
      (const __attribute__((address_space(1))) u32*)g,
      (__attribute__((address_space(3))) u32*)l, 16, 0, 0);
}

// Tiled fragment layout for K=512 GEMM operands: elt(m,k) ->
//   (m>>4)*8192 + (k>>3)*128 + (m&15)*8 + (k&7)
//
// Frag-tiled K (A-operand of S^T): per (bh, key-slab of 16): 2 half-slabs of
// 1 KB; elt(key,d) -> (bh<<16) + (key>>4)*1024 + (d>>5)*512
//                     + ((key&15) + 16*((d>>3)&3))*8 + (d&7)
// Frag-tiled V (B-operand of PV): per (bh, 64-key x 16-d slab):
//   elt(key,d) -> (bh<<16) + (key>>6)*4096 + ((d>>4)&3)*1024 + ((key>>5)&1)*512
//                 + ((d&15) + 16*((key>>3)&3))*8 + (key&7)
// Both: a 1 KB half-slab is exactly one wave's MFMA fragment in lane order,
// so global_load_lds stages it contiguously and ds_read_b128 at base+lane*16
// reads it conflict-free.

// ---------------------------------------------------------------------------
// Kernel 0a: pack mask [B,T,T] int32 -> bitmask uint64, TRANSPOSED layout
// bits[(b*16 + kt)*1024 + qrow] covering keys kt*64..kt*64+63.
// ---------------------------------------------------------------------------
__global__ __launch_bounds__(256) void pack_mask(const int* __restrict__ mask,
                                                 u64* __restrict__ bits) {
  const size_t gid = (size_t)blockIdx.x * 256 + threadIdx.x;
  const int lane = threadIdx.x & 63;
  const size_t w = gid >> 6;                 // word id = (b*1024 + q)*16 + kt
  const int v = mask[w * 64 + lane];
  const u64 b = __ballot(v != 0);
  if (lane == 0) {
    const int bb = (int)(w >> 14), q = (int)((w >> 4) & 1023), kt = (int)(w & 15);
    bits[(((size_t)(bb << 4 | kt)) << 10) | q] = b;
  }
}

// ---------------------------------------------------------------------------
// Kernel 0b: decompose fp32 [R][512] -> bf16 hi/lo in tiled fragment layout.
// ---------------------------------------------------------------------------
__global__ __launch_bounds__(256) void decompose(const float* __restrict__ src,
                                                 u16* __restrict__ hi,
                                                 u16* __restrict__ lo) {
  const int rg = blockIdx.x;
  const int t = threadIdx.x;
  const float* s = src + (size_t)rg * 16 * DIM;
  u16* ph = hi + (size_t)rg * 8192;
  u16* pl = lo + (size_t)rg * 8192;
  #pragma unroll
  for (int c = 0; c < 4; ++c) {
    const int cid = c * 256 + t;        // chunk id = kc*16 + row
    const int row = cid & 15, kc = cid >> 4;
    float f[8];
    *(float4*)&f[0] = *(const float4*)&s[row * DIM + kc * 8];
    *(float4*)&f[4] = *(const float4*)&s[row * DIM + kc * 8 + 4];
    u16 hv[8], lv[8];
    #pragma unroll
    for (int j = 0; j < 8; ++j) {
      hv[j] = f2bf(f[j]);
      lv[j] = f2bf(f[j] - bf2f(hv[j]));
    }
    *(uint4*)&ph[(size_t)cid * 8] = *(const uint4*)hv;
    *(uint4*)&pl[(size_t)cid * 8] = *(const uint4*)lv;
  }
}

// ---------------------------------------------------------------------------
// Kernel 1/3: split-bf16 MFMA GEMM (3-pass: AhBh + AhBl + AlBh), fp32-exact
// to ~2^-18.  A [M][512], B [N][512] tiled hi/lo.  128x128 tile, 4 waves.
// QKV=true: q scaled by QSCALE -> [b,h,t,d]; k/v -> frag-tiled (see above).
// ---------------------------------------------------------------------------
template <bool QKV>
__global__ __launch_bounds__(256) void mfma_gemm(
    const u16* __restrict__ Agh, const u16* __restrict__ Agl,
    const u16* __restrict__ Bgh, const u16* __restrict__ Bgl,
    const float* __restrict__ bias, void* __restrict__ out0,
    u16* __restrict__ kfr, u16* __restrict__ vfr) {
  __shared__ u16 sAh[4096];
  __shared__ u16 sAl[4096];
  __shared__ u16 sBh[4096];
  __shared__ u16 sBl[4096];

  const int tid = threadIdx.x;
  const int lane = tid & 63;
  const int wv = tid >> 6;
  const int lk = lane & 15, lq = lane >> 4;
  const int n0 = blockIdx.x * 128, m0 = blockIdx.y * 128;
  const int wm = (wv & 1) * 4;
  const int wn = (wv >> 1) * 4;

  const u16* gAh = Agh + (size_t)(m0 >> 4) * 8192 + lane * 8;
  const u16* gAl = Agl + (size_t)(m0 >> 4) * 8192 + lane * 8;
  const u16* gBh = Bgh + (size_t)(n0 >> 4) * 8192 + lane * 8;
  const u16* gBl = Bgl + (size_t)(n0 >> 4) * 8192 + lane * 8;

  f32x4 acc[4][4];
  #pragma unroll
  for (int i = 0; i < 4; ++i)
    #pragma unroll
    for (int j = 0; j < 4; ++j) acc[i][j] = (f32x4){0.f, 0.f, 0.f, 0.f};

  #pragma unroll 1
  for (int ki = 0; ki < 16; ++ki) {
    __syncthreads();
    #pragma unroll
    for (int it = 0; it < 2; ++it) {
      const int t = it * 4 + wv;
      const size_t go = (size_t)t * 8192 + ki * 512;
      const int lo_ = t * 512 + lane * 8;
      a16(gAh + go, &sAh[lo_]);
      a16(gAl + go, &sAl[lo_]);
      a16(gBh + go, &sBh[lo_]);
      a16(gBl + go, &sBl[lo_]);
    }
    __syncthreads();

    bf16x8 ah[4], al[4], bh[4], bl[4];
    #pragma unroll
    for (int i = 0; i < 4; ++i) {
      ah[i] = *(const bf16x8*)&sAh[(wm + i) * 512 + lane * 8];
      al[i] = *(const bf16x8*)&sAl[(wm + i) * 512 + lane * 8];
      bh[i] = *(const bf16x8*)&sBh[(wn + i) * 512 + lane * 8];
      bl[i] = *(const bf16x8*)&sBl[(wn + i) * 512 + lane * 8];
    }
    #pragma unroll
    for (int i = 0; i < 4; ++i)
      #pragma unroll
      for (int j = 0; j < 4; ++j) {
        acc[i][j] = __builtin_amdgcn_mfma_f32_16x16x32_bf16(ah[i], bh[j], acc[i][j], 0, 0, 0);
        acc[i][j] = __builtin_amdgcn_mfma_f32_16x16x32_bf16(ah[i], bl[j], acc[i][j], 0, 0, 0);
        acc[i][j] = __builtin_amdgcn_mfma_f32_16x16x32_bf16(al[i], bh[j], acc[i][j], 0, 0, 0);
      }
  }

  // Epilogue. C/D layout: col = lk (n), row = lq*4 + r (m).
  #pragma unroll
  for (int j = 0; j < 4; ++j) {
    const int n = n0 + (wn + j) * 16 + lk;
    const float bv_ = bias[n];
    #pragma unroll
    for (int i = 0; i < 4; ++i) {
      const int mb = m0 + (wm + i) * 16 + lq * 4;
      if (QKV) {
        const int which = n >> 9, h = (n >> 6) & 7, d = n & 63;
        const int b = mb >> 10, tok0 = mb & 1023;    // tok0 & 15 == lq*4
        const size_t hb = (size_t)((b << 3) + h) << 16;
        if (which == 2) {           // V frag-tiled, one 8-B store (keys r=0..3)
          const size_t base = hb + ((size_t)(tok0 >> 6) << 12) +
                              ((size_t)((d >> 4) & 3) << 10) +
                              ((size_t)((tok0 >> 5) & 1) << 9) +
                              ((size_t)((d & 15) + (((tok0 >> 3) & 3) << 4)) << 3) +
                              (size_t)(tok0 & 7);
          uint2 o2;
          o2.x = pk2(acc[i][j][0] + bv_, acc[i][j][1] + bv_);
          o2.y = pk2(acc[i][j][2] + bv_, acc[i][j][3] + bv_);
          *(uint2*)&vfr[base] = o2;
        } else if (which == 1) {    // K frag-tiled, 4 scalar stores
          const size_t base = hb + ((size_t)(tok0 >> 4) << 10) +
                              ((size_t)(d >> 5) << 9) + (size_t)(d & 7) +
                              ((size_t)(((d >> 3) & 3) << 4) << 3);
          #pragma unroll
          for (int r = 0; r < 4; ++r)
            kfr[base + (((tok0 & 15) + r) << 3)] = f2bf(acc[i][j][r] + bv_);
        } else {                    // Q (scaled): [b,h,t,d]
          u16* dst = (u16*)out0;
          #pragma unroll
          for (int r = 0; r < 4; ++r)
            dst[(((size_t)((b << 3) + h) << 10 | (tok0 + r)) << 6) + d] =
                f2bf((acc[i][j][r] + bv_) * QSCALE);
        }
      } else {
        #pragma unroll
        for (int r = 0; r < 4; ++r)
          ((float*)out0)[(size_t)(mb + r) * DIM + n] = acc[i][j][r] + bv_;
      }
    }
  }
}

// ---------------------------------------------------------------------------
// Kernel 2: flash attention, cooperative async LDS staging of frag-tiled K/V.
// S^T via mfma(A=K, B=Q) -> thread holds 4 k-contiguous P values (one b64
// write to wave-private Ps strip); PV A-frag reads own row, no barrier there.
// No-max softmax: Q pre-scaled by 0.125*log2e, p = exp2(s), l summed at end.
// Grid (64 heads, 16 qtiles): linear bid % 8 == head % 8 -> per-head K/V stays
// in one XCD's L2.
// ---------------------------------------------------------------------------
__global__ __launch_bounds__(256) void attn_mfma(
    const u16* __restrict__ qg, const u16* __restrict__ kfr,
    const u16* __restrict__ vfr, const u64* __restrict__ bitsT,
    u16* __restrict__ ohi, u16* __restrict__ olo) {
  __shared__ u16 Kls[4096];     // 4 A-frag slabs (16 key x 64 d)
  __shared__ u16 Vls[4096];     // 4 B-frag slabs (64 key x 16 d)
  __shared__ u16 Ps[64 * 72];   // [q][k] stride 72, wave-private rows

  const int tid = threadIdx.x;
  const int lane = tid & 63;
  const int wv = tid >> 6;
  const int lk = lane & 15, lq = lane >> 4;
  const int bh = blockIdx.x;              // head fastest -> XCD locality
  const int q0 = blockIdx.y * 64;
  const int bb = bh >> 3;
  const int q = q0 + wv * 16 + lk;        // this thread's softmax row

  // Q B-frags (n=q), hoisted across all k-tiles.
  const u16* qrow = qg + ((size_t)(bh << 10 | q) << 6);
  const bf16x8 bq0 = *(const bf16x8*)(qrow + lq * 8);
  const bf16x8 bq1 = *(const bf16x8*)(qrow + 32 + lq * 8);

  const u16* kh = kfr + ((size_t)bh << 16);
  const u16* vh = vfr + ((size_t)bh << 16);
  const u64* bitp = bitsT + ((size_t)bb << 14) + q;
  u16* pw = &Ps[(wv * 16 + lk) * 72];     // wave-private P row (own q)

  f32x4 o_[4];
  float l = 0.f;
  #pragma unroll
  for (int t = 0; t < 4; ++t) o_[t] = (f32x4){0.f, 0.f, 0.f, 0.f};

  #pragma unroll 1
  for (int kt = 0; kt < 16; ++kt) {
    __syncthreads();   // protect Kls/Vls from previous iteration's readers
    #pragma unroll
    for (int it = 0; it < 2; ++it) {
      const int c = it * 4 + wv;          // 1 KB chunk staged by this wave
      const int off = c * 512 + lane * 8;
      a16(kh + (size_t)(kt << 12) + off, &Kls[off]);
      a16(vh + (size_t)(kt << 12) + off, &Vls[off]);
    }
    const u64 wd = bitp[kt << 10];
    __syncthreads();   // vmcnt drain: tiles ready

    // S^T: D[m=key-local][n=q]; A = K slabs, B = own-q frags.
    f32x4 st[4];
    const f32x4 z4 = (f32x4){0.f, 0.f, 0.f, 0.f};
    #pragma unroll
    for (int t = 0; t < 4; ++t) {
      const bf16x8 ak0 = *(const bf16x8*)&Kls[t * 1024 + lane * 8];
      const bf16x8 ak1 = *(const bf16x8*)&Kls[t * 1024 + 512 + lane * 8];
      f32x4 a = __builtin_amdgcn_mfma_f32_16x16x32_bf16(ak0, bq0, z4, 0, 0, 0);
      st[t] = __builtin_amdgcn_mfma_f32_16x16x32_bf16(ak1, bq1, a, 0, 0, 0);
    }

    // Masked exp2 (no max subtraction), partial l, packed b64 P writes.
    const u32 w0 = (u32)wd, w1 = (u32)(wd >> 32);
    #pragma unroll
    for (int t = 0; t < 4; ++t) {
      const u32 w = (t < 2) ? w0 : w1;
      const int base = (t & 1) * 16 + lq * 4;
      float p[4];
      #pragma unroll
      for (int r = 0; r < 4; ++r) {
        const float sv = ((w >> (base + r)) & 1u) ? -INFINITY : st[t][r];
        p[r] = __builtin_amdgcn_exp2f(sv);
        l += p[r];
      }
      *(uint2*)(pw + t * 16 + lq * 4) = uint2{pk2(p[0], p[1]), pk2(p[2], p[3])};
    }

    // PV: A = own P row (wave-private, lgkmcnt only); B = V slabs.
    const bf16x8 pa0 = *(const bf16x8*)(pw + lq * 8);
    const bf16x8 pa1 = *(const bf16x8*)(pw + 32 + lq * 8);
    #pragma unroll
    for (int t = 0; t < 4; ++t) {
      const bf16x8 vb0 = *(const bf16x8*)&Vls[t * 1024 + lane * 8];
      const bf16x8 vb1 = *(const bf16x8*)&Vls[t * 1024 + 512 + lane * 8];
      o_[t] = __builtin_amdgcn_mfma_f32_16x16x32_bf16(pa0, vb0, o_[t], 0, 0, 0);
      o_[t] = __builtin_amdgcn_mfma_f32_16x16x32_bf16(pa1, vb1, o_[t], 0, 0, 0);
    }
  }

  // Row-sum l lives split across the 4 lq groups: reduce once.
  l += __shfl_xor(l, 16);
  l += __shfl_xor(l, 32);

  // Epilogue: normalize; emit tiled hi/lo for proj GEMM (k = h*64+d).
  const int h = bh & 7;
  #pragma unroll
  for (int r = 0; r < 4; ++r) {
    const float inv = 1.0f / __shfl(l, lq * 4 + r);
    const int tok = q0 + wv * 16 + lq * 4 + r;
    const int m = (bb << 10) | tok;
    const size_t rgo = (size_t)(m >> 4) * 8192 + (size_t)(m & 15) * 8;
    #pragma unroll
    for (int t = 0; t < 4; ++t) {
      const int d = t * 16 + lk;
      const int k = (h << 6) | d;
      const float v = o_[t][r] * inv;
      const u16 hv = f2bf(v);
      const size_t off = rgo + (size_t)(k >> 3) * 128 + (k & 7);
      ohi[off] = hv;
      olo[off] = f2bf(v - bf2f(hv));
    }
  }
}

// ---------------------------------------------------------------------------
extern "C" void kernel_launch(void* const* d_in, const int* in_sizes, int n_in,
                              void* d_out, int out_size, void* d_ws,
                              size_t ws_size, hipStream_t stream) {
  const float* x      = (const float*)d_in[0];
  const int*   mask   = (const int*)d_in[1];   // jax bool -> int32
  const float* qkv_w  = (const float*)d_in[2];
  const float* qkv_b  = (const float*)d_in[3];
  const float* proj_w = (const float*)d_in[4];
  const float* proj_b = (const float*)d_in[5];
  float* out = (float*)d_out;

  // Workspace: bits | qb kfr vfr | xhi xlo | ohi olo | wqh wql | wph wpl
  const size_t SZ = (size_t)BATCH * NH * SEQ * HD;   // 4,194,304 elts
  u64* bits = (u64*)d_ws;                            // 1 MB
  u16* qb  = (u16*)(bits + 131072);
  u16* kfr = qb + SZ;
  u16* vfr = kfr + SZ;
  u16* xhi = vfr + SZ;
  u16* xlo = xhi + SZ;
  u16* ohi = xlo + SZ;
  u16* olo = ohi + SZ;
  u16* wqh = olo + SZ;
  u16* wql = wqh + 1536 * 512;
  u16* wph = wql + 1536 * 512;
  u16* wpl = wph + 512 * 512;

  pack_mask<<<(BATCH * SEQ * SEQ) / 256, 256, 0, stream>>>(mask, bits);
  decompose<<<8192 / 16, 256, 0, stream>>>(x, xhi, xlo);
  decompose<<<1536 / 16, 256, 0, stream>>>(qkv_w, wqh, wql);
  decompose<<<512 / 16, 256, 0, stream>>>(proj_w, wph, wpl);

  mfma_gemm<true><<<dim3(12, 64), 256, 0, stream>>>(
      xhi, xlo, wqh, wql, qkv_b, qb, kfr, vfr);
  attn_mfma<<<dim3(64, SEQ / 64), 256, 0, stream>>>(
      qb, kfr, vfr, bits, ohi, olo);
  mfma_gemm<false><<<dim3(4, 64), 256, 0, stream>>>(
      ohi, olo, wph, wpl, proj_b, out, nullptr, nullptr);
}

// Round 7
// 214.867 us; speedup vs baseline: 1.4031x; 1.0223x over previous
//
#include <hip/hip_runtime.h>
#include <math.h>

// Problem constants (PointMAE self-attention)
#define DIM   512
#define NH    8
#define HD    64
#define BATCH 8
#define SEQ   1024
// 0.125 * log2(e): folded into Q at the qkv epilogue so attn uses exp2 directly.
#define QSCALE 0.18033688011112042f

typedef unsigned short u16;
typedef unsigned int   u32;
typedef unsigned long long u64;
typedef __bf16 bf16x8 __attribute__((ext_vector_type(8)));
typedef float  f32x4  __attribute__((ext_vector_type(4)));

__device__ inline u16 f2bf(float f) {   // fp32 -> bf16 RNE
  u32 u = __builtin_bit_cast(u32, f);
  return (u16)((u + 0x7fffu + ((u >> 16) & 1u)) >> 16);
}
__device__ inline float bf2f(u16 h) {
  return __builtin_bit_cast(float, (u32)h << 16);
}
__device__ inline u32 pk2(float a, float b) {  // packed RNE bf16 pair
  return (u32)f2bf(a) | ((u32)f2bf(b) << 16);
}

// Async global->LDS, 16 B per lane. LDS side must be base + lane*16.
__device__ inline void a16(const u16* g, u16* l) {
  __builtin_amdgcn_global_load_lds(
      (const __attribute__((address_space(1))) u32*)g,
      (__attribute__((address_space(3))) u32*)l, 16, 0, 0);
}

// Tiled fragment layout for K=512 GEMM operands: elt(m,k) ->
//   (m>>4)*8192 + (k>>3)*128 + (m&15)*8 + (k&7)
// Frag-tiled K/V layouts for attention: see R6 comments (unchanged).

// ---------------------------------------------------------------------------
// Kernel 0 (fused prep): range-dispatched on blockIdx.x.
//   [0, 32768)        : pack mask [B,T,T] int32 -> transposed bitmask u64
//   [32768, 33280)    : decompose x (512 row-groups)
//   [33280, 33376)    : decompose qkv_w (96 row-groups)
//   [33376, 33408)    : decompose proj_w (32 row-groups)
// ---------------------------------------------------------------------------
__device__ inline void decomp_body(const float* __restrict__ src, u16* ph,
                                   u16* pl, int t) {
  #pragma unroll
  for (int c = 0; c < 4; ++c) {
    const int cid = c * 256 + t;        // chunk id = kc*16 + row
    const int row = cid & 15, kc = cid >> 4;
    float f[8];
    *(float4*)&f[0] = *(const float4*)&src[row * DIM + kc * 8];
    *(float4*)&f[4] = *(const float4*)&src[row * DIM + kc * 8 + 4];
    u16 hv[8], lv[8];
    #pragma unroll
    for (int j = 0; j < 8; ++j) {
      hv[j] = f2bf(f[j]);
      lv[j] = f2bf(f[j] - bf2f(hv[j]));
    }
    *(uint4*)&ph[(size_t)cid * 8] = *(const uint4*)hv;
    *(uint4*)&pl[(size_t)cid * 8] = *(const uint4*)lv;
  }
}

__global__ __launch_bounds__(256) void prep(
    const int* __restrict__ mask, u64* __restrict__ bits,
    const float* __restrict__ x, u16* __restrict__ xhi, u16* __restrict__ xlo,
    const float* __restrict__ qkvw, u16* __restrict__ wqh, u16* __restrict__ wql,
    const float* __restrict__ projw, u16* __restrict__ wph, u16* __restrict__ wpl) {
  const int blk = blockIdx.x;
  const int t = threadIdx.x;
  if (blk < 32768) {
    const size_t gid = (size_t)blk * 256 + t;
    const int lane = t & 63;
    const size_t w = gid >> 6;               // word id = (b*1024 + q)*16 + kt
    const int v = mask[w * 64 + lane];
    const u64 b = __ballot(v != 0);
    if (lane == 0) {
      const int bb = (int)(w >> 14), q = (int)((w >> 4) & 1023),
                kt = (int)(w & 15);
      bits[(((size_t)(bb << 4 | kt)) << 10) | q] = b;
    }
  } else if (blk < 33280) {
    const int rg = blk - 32768;
    decomp_body(x + (size_t)rg * 16 * DIM, xhi + (size_t)rg * 8192,
                xlo + (size_t)rg * 8192, t);
  } else if (blk < 33376) {
    const int rg = blk - 33280;
    decomp_body(qkvw + (size_t)rg * 16 * DIM, wqh + (size_t)rg * 8192,
                wql + (size_t)rg * 8192, t);
  } else {
    const int rg = blk - 33376;
    decomp_body(projw + (size_t)rg * 16 * DIM, wph + (size_t)rg * 8192,
                wpl + (size_t)rg * 8192, t);
  }
}

// ---------------------------------------------------------------------------
// Kernel 1/3: split-bf16 MFMA GEMM (3-pass: AhBh + AhBl + AlBh), fp32-exact
// to ~2^-18.  A [M][512], B [N][512] tiled hi/lo.  128x128 tile, 4 waves.
// Grid (64 m-blocks, N/128 n-blocks): linear id % 8 == m-block % 8 so all
// n-blocks sharing an A-tile land on one XCD (A 2 MB + W 3 MB ~ L2-resident).
// QKV=true: q scaled by QSCALE -> [b,h,t,d]; k/v -> frag-tiled.
// ---------------------------------------------------------------------------
template <bool QKV>
__global__ __launch_bounds__(256) void mfma_gemm(
    const u16* __restrict__ Agh, const u16* __restrict__ Agl,
    const u16* __restrict__ Bgh, const u16* __restrict__ Bgl,
    const float* __restrict__ bias, void* __restrict__ out0,
    u16* __restrict__ kfr, u16* __restrict__ vfr) {
  __shared__ u16 sAh[4096];
  __shared__ u16 sAl[4096];
  __shared__ u16 sBh[4096];
  __shared__ u16 sBl[4096];

  const int tid = threadIdx.x;
  const int lane = tid & 63;
  const int wv = tid >> 6;
  const int lk = lane & 15, lq = lane >> 4;
  const int m0 = blockIdx.x * 128, n0 = blockIdx.y * 128;   // m fastest: XCD
  const int wm = (wv & 1) * 4;
  const int wn = (wv >> 1) * 4;

  const u16* gAh = Agh + (size_t)(m0 >> 4) * 8192 + lane * 8;
  const u16* gAl = Agl + (size_t)(m0 >> 4) * 8192 + lane * 8;
  const u16* gBh = Bgh + (size_t)(n0 >> 4) * 8192 + lane * 8;
  const u16* gBl = Bgl + (size_t)(n0 >> 4) * 8192 + lane * 8;

  f32x4 acc[4][4];
  #pragma unroll
  for (int i = 0; i < 4; ++i)
    #pragma unroll
    for (int j = 0; j < 4; ++j) acc[i][j] = (f32x4){0.f, 0.f, 0.f, 0.f};

  #pragma unroll 1
  for (int ki = 0; ki < 16; ++ki) {
    __syncthreads();
    #pragma unroll
    for (int it = 0; it < 2; ++it) {
      const int t = it * 4 + wv;
      const size_t go = (size_t)t * 8192 + ki * 512;
      const int lo_ = t * 512 + lane * 8;
      a16(gAh + go, &sAh[lo_]);
      a16(gAl + go, &sAl[lo_]);
      a16(gBh + go, &sBh[lo_]);
      a16(gBl + go, &sBl[lo_]);
    }
    __syncthreads();

    bf16x8 ah[4], al[4], bh[4], bl[4];
    #pragma unroll
    for (int i = 0; i < 4; ++i) {
      ah[i] = *(const bf16x8*)&sAh[(wm + i) * 512 + lane * 8];
      al[i] = *(const bf16x8*)&sAl[(wm + i) * 512 + lane * 8];
      bh[i] = *(const bf16x8*)&sBh[(wn + i) * 512 + lane * 8];
      bl[i] = *(const bf16x8*)&sBl[(wn + i) * 512 + lane * 8];
    }
    #pragma unroll
    for (int i = 0; i < 4; ++i)
      #pragma unroll
      for (int j = 0; j < 4; ++j) {
        acc[i][j] = __builtin_amdgcn_mfma_f32_16x16x32_bf16(ah[i], bh[j], acc[i][j], 0, 0, 0);
        acc[i][j] = __builtin_amdgcn_mfma_f32_16x16x32_bf16(ah[i], bl[j], acc[i][j], 0, 0, 0);
        acc[i][j] = __builtin_amdgcn_mfma_f32_16x16x32_bf16(al[i], bh[j], acc[i][j], 0, 0, 0);
      }
  }

  // Epilogue. C/D layout: col = lk (n), row = lq*4 + r (m).
  #pragma unroll
  for (int j = 0; j < 4; ++j) {
    const int n = n0 + (wn + j) * 16 + lk;
    const float bv_ = bias[n];
    #pragma unroll
    for (int i = 0; i < 4; ++i) {
      const int mb = m0 + (wm + i) * 16 + lq * 4;
      if (QKV) {
        const int which = n >> 9, h = (n >> 6) & 7, d = n & 63;
        const int b = mb >> 10, tok0 = mb & 1023;    // tok0 & 15 == lq*4
        const size_t hb = (size_t)((b << 3) + h) << 16;
        if (which == 2) {           // V frag-tiled, one 8-B store (keys r=0..3)
          const size_t base = hb + ((size_t)(tok0 >> 6) << 12) +
                              ((size_t)((d >> 4) & 3) << 10) +
                              ((size_t)((tok0 >> 5) & 1) << 9) +
                              ((size_t)((d & 15) + (((tok0 >> 3) & 3) << 4)) << 3) +
                              (size_t)(tok0 & 7);
          uint2 o2;
          o2.x = pk2(acc[i][j][0] + bv_, acc[i][j][1] + bv_);
          o2.y = pk2(acc[i][j][2] + bv_, acc[i][j][3] + bv_);
          *(uint2*)&vfr[base] = o2;
        } else if (which == 1) {    // K frag-tiled, 4 scalar stores
          const size_t base = hb + ((size_t)(tok0 >> 4) << 10) +
                              ((size_t)(d >> 5) << 9) + (size_t)(d & 7) +
                              ((size_t)(((d >> 3) & 3) << 4) << 3);
          #pragma unroll
          for (int r = 0; r < 4; ++r)
            kfr[base + (((tok0 & 15) + r) << 3)] = f2bf(acc[i][j][r] + bv_);
        } else {                    // Q (scaled): [b,h,t,d]
          u16* dst = (u16*)out0;
          #pragma unroll
          for (int r = 0; r < 4; ++r)
            dst[(((size_t)((b << 3) + h) << 10 | (tok0 + r)) << 6) + d] =
                f2bf((acc[i][j][r] + bv_) * QSCALE);
        }
      } else {
        #pragma unroll
        for (int r = 0; r < 4; ++r)
          ((float*)out0)[(size_t)(mb + r) * DIM + n] = acc[i][j][r] + bv_;
      }
    }
  }
}

// ---------------------------------------------------------------------------
// Kernel 2: flash attention, cooperative async LDS staging of frag-tiled K/V.
// S^T via mfma(A=K, B=Q); no-max softmax (Q pre-scaled), wave-private P strip.
// Grid (64 heads, 16 qtiles): head fastest -> per-head K/V stays in one XCD L2.
// ---------------------------------------------------------------------------
__global__ __launch_bounds__(256) void attn_mfma(
    const u16* __restrict__ qg, const u16* __restrict__ kfr,
    const u16* __restrict__ vfr, const u64* __restrict__ bitsT,
    u16* __restrict__ ohi, u16* __restrict__ olo) {
  __shared__ u16 Kls[4096];     // 4 A-frag slabs (16 key x 64 d)
  __shared__ u16 Vls[4096];     // 4 B-frag slabs (64 key x 16 d)
  __shared__ u16 Ps[64 * 72];   // [q][k] stride 72, wave-private rows

  const int tid = threadIdx.x;
  const int lane = tid & 63;
  const int wv = tid >> 6;
  const int lk = lane & 15, lq = lane >> 4;
  const int bh = blockIdx.x;              // head fastest -> XCD locality
  const int q0 = blockIdx.y * 64;
  const int bb = bh >> 3;
  const int q = q0 + wv * 16 + lk;        // this thread's softmax row

  // Q B-frags (n=q), hoisted across all k-tiles.
  const u16* qrow = qg + ((size_t)(bh << 10 | q) << 6);
  const bf16x8 bq0 = *(const bf16x8*)(qrow + lq * 8);
  const bf16x8 bq1 = *(const bf16x8*)(qrow + 32 + lq * 8);

  const u16* kh = kfr + ((size_t)bh << 16);
  const u16* vh = vfr + ((size_t)bh << 16);
  const u64* bitp = bitsT + ((size_t)bb << 14) + q;
  u16* pw = &Ps[(wv * 16 + lk) * 72];     // wave-private P row (own q)

  f32x4 o_[4];
  float l = 0.f;
  #pragma unroll
  for (int t = 0; t < 4; ++t) o_[t] = (f32x4){0.f, 0.f, 0.f, 0.f};

  #pragma unroll 1
  for (int kt = 0; kt < 16; ++kt) {
    __syncthreads();   // protect Kls/Vls from previous iteration's readers
    #pragma unroll
    for (int it = 0; it < 2; ++it) {
      const int c = it * 4 + wv;          // 1 KB chunk staged by this wave
      const int off = c * 512 + lane * 8;
      a16(kh + (size_t)(kt << 12) + off, &Kls[off]);
      a16(vh + (size_t)(kt << 12) + off, &Vls[off]);
    }
    const u64 wd = bitp[kt << 10];
    __syncthreads();   // vmcnt drain: tiles ready

    // S^T: D[m=key-local][n=q]; A = K slabs, B = own-q frags.
    f32x4 st[4];
    const f32x4 z4 = (f32x4){0.f, 0.f, 0.f, 0.f};
    #pragma unroll
    for (int t = 0; t < 4; ++t) {
      const bf16x8 ak0 = *(const bf16x8*)&Kls[t * 1024 + lane * 8];
      const bf16x8 ak1 = *(const bf16x8*)&Kls[t * 1024 + 512 + lane * 8];
      f32x4 a = __builtin_amdgcn_mfma_f32_16x16x32_bf16(ak0, bq0, z4, 0, 0, 0);
      st[t] = __builtin_amdgcn_mfma_f32_16x16x32_bf16(ak1, bq1, a, 0, 0, 0);
    }

    // Masked exp2 (no max subtraction), partial l, packed b64 P writes.
    const u32 w0 = (u32)wd, w1 = (u32)(wd >> 32);
    #pragma unroll
    for (int t = 0; t < 4; ++t) {
      const u32 w = (t < 2) ? w0 : w1;
      const int base = (t & 1) * 16 + lq * 4;
      float p[4];
      #pragma unroll
      for (int r = 0; r < 4; ++r) {
        const float sv = ((w >> (base + r)) & 1u) ? -INFINITY : st[t][r];
        p[r] = __builtin_amdgcn_exp2f(sv);
        l += p[r];
      }
      *(uint2*)(pw + t * 16 + lq * 4) = uint2{pk2(p[0], p[1]), pk2(p[2], p[3])};
    }

    // PV: A = own P row (wave-private, lgkmcnt only); B = V slabs.
    const bf16x8 pa0 = *(const bf16x8*)(pw + lq * 8);
    const bf16x8 pa1 = *(const bf16x8*)(pw + 32 + lq * 8);
    #pragma unroll
    for (int t = 0; t < 4; ++t) {
      const bf16x8 vb0 = *(const bf16x8*)&Vls[t * 1024 + lane * 8];
      const bf16x8 vb1 = *(const bf16x8*)&Vls[t * 1024 + 512 + lane * 8];
      o_[t] = __builtin_amdgcn_mfma_f32_16x16x32_bf16(pa0, vb0, o_[t], 0, 0, 0);
      o_[t] = __builtin_amdgcn_mfma_f32_16x16x32_bf16(pa1, vb1, o_[t], 0, 0, 0);
    }
  }

  // Row-sum l lives split across the 4 lq groups: reduce once.
  l += __shfl_xor(l, 16);
  l += __shfl_xor(l, 32);

  // Epilogue: normalize; emit tiled hi/lo for proj GEMM (k = h*64+d).
  const int h = bh & 7;
  #pragma unroll
  for (int r = 0; r < 4; ++r) {
    const float inv = 1.0f / __shfl(l, lq * 4 + r);
    const int tok = q0 + wv * 16 + lq * 4 + r;
    const int m = (bb << 10) | tok;
    const size_t rgo = (size_t)(m >> 4) * 8192 + (size_t)(m & 15) * 8;
    #pragma unroll
    for (int t = 0; t < 4; ++t) {
      const int d = t * 16 + lk;
      const int k = (h << 6) | d;
      const float v = o_[t][r] * inv;
      const u16 hv = f2bf(v);
      const size_t off = rgo + (size_t)(k >> 3) * 128 + (k & 7);
      ohi[off] = hv;
      olo[off] = f2bf(v - bf2f(hv));
    }
  }
}

// ---------------------------------------------------------------------------
extern "C" void kernel_launch(void* const* d_in, const int* in_sizes, int n_in,
                              void* d_out, int out_size, void* d_ws,
                              size_t ws_size, hipStream_t stream) {
  const float* x      = (const float*)d_in[0];
  const int*   mask   = (const int*)d_in[1];   // jax bool -> int32
  const float* qkv_w  = (const float*)d_in[2];
  const float* qkv_b  = (const float*)d_in[3];
  const float* proj_w = (const float*)d_in[4];
  const float* proj_b = (const float*)d_in[5];
  float* out = (float*)d_out;

  // Workspace: bits | qb kfr vfr | xhi xlo | ohi olo | wqh wql | wph wpl
  const size_t SZ = (size_t)BATCH * NH * SEQ * HD;   // 4,194,304 elts
  u64* bits = (u64*)d_ws;                            // 1 MB
  u16* qb  = (u16*)(bits + 131072);
  u16* kfr = qb + SZ;
  u16* vfr = kfr + SZ;
  u16* xhi = vfr + SZ;
  u16* xlo = xhi + SZ;
  u16* ohi = xlo + SZ;
  u16* olo = ohi + SZ;
  u16* wqh = olo + SZ;
  u16* wql = wqh + 1536 * 512;
  u16* wph = wql + 1536 * 512;
  u16* wpl = wph + 512 * 512;

  prep<<<33408, 256, 0, stream>>>(mask, bits, x, xhi, xlo,
                                  qkv_w, wqh, wql, proj_w, wph, wpl);
  mfma_gemm<true><<<dim3(64, 12), 256, 0, stream>>>(
      xhi, xlo, wqh, wql, qkv_b, qb, kfr, vfr);
  attn_mfma<<<dim3(64, SEQ / 64), 256, 0, stream>>>(
      qb, kfr, vfr, bits, ohi, olo);
  mfma_gemm<false><<<dim3(64, 4), 256, 0, stream>>>(
      ohi, olo, wph, wpl, proj_b, out, nullptr, nullptr);
}